// Round 5
// baseline (580.440 us; speedup 1.0000x reference)
//
#include <hip/hip_runtime.h>

// ManifoldConstrainedHyperConnection fused kernel.
// Shapes: x (8192 tokens, 4 streams, 2048 dim) fp32; W_router (24, 2048); b_router (24).
// out (8192, 4, 2048) fp32.
//
// Round 5 redesign: ONE WAVE PER TOKEN, zero barriers, zero LDS.
// History: block-per-token variants (r0-r4) all sat at 204-285us, latency-bound
// (VALUBusy ~13%, HBM ~25-37%, occ ~32-41%): 26 four-wave barriers + un-double-
// buffered W staging exposed ~1-2k cy of loaded-L2 latency 12x per block, and
// residency never exceeded ~10 waves/CU, so the stalls didn't overlap.
// Now: each 64-lane wave owns one token end-to-end (4 independent waves per
// 256-thread block). Lane owns 32 d-cols (8 f32x4, stride-64 interleave ->
// every access is a 1KB fully-coalesced wave transaction). Router logits via
// in-wave butterflies: full 6-level xor for the 8 softmax logits, and a
// reduce-SCATTER butterfly (pair-halving, cndmask-selected, statically
// indexed) for the 16 residual logits so lane l ends holding the full sum of
// residual cell (l&15) -- no runtime array indexing, no LDS round-trip.
// Sinkhorn runs replicated in every 16-lane group (uniform inputs, zero
// divergence). x is NOT held across the kernel: the epilogue re-reads it from
// L2/L3 (its lines are hot from phase 1), keeping VGPR ~100 so ~20 waves/CU
// can co-hide latency. No __syncthreads anywhere.

#define SINKHORN_ITERS 4
#define EPSV 1e-6f

typedef float f32x4 __attribute__((ext_vector_type(4)));

__global__ __launch_bounds__(256, 4) void mchc_fused(
    const float* __restrict__ x,
    const float* __restrict__ Wr,
    const float* __restrict__ br,
    float* __restrict__ out)
{
    const int lane  = threadIdx.x & 63;
    const int wave  = threadIdx.x >> 6;
    const int token = blockIdx.x * 4 + wave;     // one token per wave

    const f32x4* __restrict__ x4 = (const f32x4*)(x + (size_t)token * 8192);
    const f32x4* __restrict__ w4 = (const f32x4*)Wr;
    f32x4*       __restrict__ o4 = (f32x4*)(out + (size_t)token * 8192);

    // ---- Phase 1: stream-sum. Lane's chunks: f32x4 index k*64 + lane, k=0..7.
    // 32 independent coalesced loads; s = x0+x1+x2+x3 (mean*4; 0.25 folded later).
    f32x4 s[8];
#pragma unroll
    for (int k = 0; k < 8; ++k) s[k] = x4[k * 64 + lane];
#pragma unroll
    for (int w = 1; w < 4; ++w)
#pragma unroll
        for (int k = 0; k < 8; ++k) s[k] += x4[w * 512 + k * 64 + lane];

    // ---- Phase 2: 24 router-row partial dots over this lane's 32 cols.
    // Rows are independent; compiler pipelines loads of row r+1 under row r's
    // FMAs (register headroom ~40 regs is ample -- no forced staging this time).
    float p[24];
#pragma unroll
    for (int r = 0; r < 24; ++r) {
        f32x4 t = s[0] * w4[r * 512 + lane];
#pragma unroll
        for (int k = 1; k < 8; ++k)
            t += s[k] * w4[r * 512 + k * 64 + lane];
        p[r] = t.x + t.y + t.z + t.w;
    }

    // ---- Phase 3a: full butterfly for the 8 softmax logits (sum in all lanes).
    float raw[8];
#pragma unroll
    for (int k = 0; k < 8; ++k) {
        float v = p[k];
#pragma unroll
        for (int d = 1; d < 64; d <<= 1) v += __shfl_xor(v, d);
        raw[k] = 0.25f * v + br[k];
    }

    // ---- Phase 3b: reduce-scatter the 16 residual logits.
    // Invariant: at step t, q[u] (u < 16>>t) holds the partial of original
    // cell m = (u<<t) | (lane & ((1<<t)-1)), reduced over lanes differing in
    // bits 0..t-1. Pair (q[2v], q[2v+1]) differs in bit t of m; each lane
    // keeps the half matching its own bit t and receives the partner's
    // partial of that same cell. After t=0..3 plus two plain butterfly steps,
    // lane l holds the full sum of residual cell (l&15). All indices static.
    float q[16];
#pragma unroll
    for (int m = 0; m < 16; ++m) q[m] = p[8 + m];
#pragma unroll
    for (int t = 0; t < 4; ++t) {
        const int d = 1 << t;
        const bool hi = (lane & d) != 0;
#pragma unroll
        for (int v = 0; v < (8 >> t); ++v) {
            float a = q[2 * v], b = q[2 * v + 1];
            float keep = hi ? b : a;
            float send = hi ? a : b;
            q[v] = keep + __shfl_xor(send, d);
        }
    }
    float rsum = q[0];
    rsum += __shfl_xor(rsum, 16);
    rsum += __shfl_xor(rsum, 32);
    const float rw = 0.25f * rsum + br[8 + (lane & 15)];

    // ---- Phase 4: softmaxes + sinkhorn, replicated in every 16-lane group.
    const int i = (lane >> 2) & 3, j = lane & 3;

    float mp = fmaxf(fmaxf(raw[0], raw[1]), fmaxf(raw[2], raw[3]));
    float e0 = __expf(raw[0] - mp), e1 = __expf(raw[1] - mp);
    float e2 = __expf(raw[2] - mp), e3 = __expf(raw[3] - mp);
    float sp = e0 + e1 + e2 + e3;
    float pre_j = ((j & 1) ? ((j & 2) ? e3 : e1) : ((j & 2) ? e2 : e0)) / sp;

    float mq = fmaxf(fmaxf(raw[4], raw[5]), fmaxf(raw[6], raw[7]));
    float f0 = __expf(raw[4] - mq), f1 = __expf(raw[5] - mq);
    float f2 = __expf(raw[6] - mq), f3 = __expf(raw[7] - mq);
    float sq = f0 + f1 + f2 + f3;
    float post_i = ((i & 1) ? ((i & 2) ? f3 : f1) : ((i & 2) ? f2 : f0)) / sq;

    // residual logits + (-2 off-diag, +2 diag) bias, exponentiate
    float w = __expf(rw + ((i == j) ? 2.0f : -2.0f));
#pragma unroll
    for (int it = 0; it < SINKHORN_ITERS; ++it) {
        // row normalize: sum over j (lane bits 0..1)
        float rs = w + __shfl_xor(w, 1);
        rs += __shfl_xor(rs, 2);
        w /= fmaxf(rs, EPSV);
        // col normalize: sum over i (lane bits 2..3)
        float cs = w + __shfl_xor(w, 4);
        cs += __shfl_xor(cs, 8);
        w /= fmaxf(cs, EPSV);
    }
    const float Mval = w + post_i * pre_j;   // fold post[i]*pre[j] into the mix

    // broadcast the 4x4 mix to all lanes (16 wave-uniform shuffles)
    float M[16];
#pragma unroll
    for (int m = 0; m < 16; ++m) M[m] = __shfl(Mval, m);

    // ---- Phase 5: re-read x (L2/L3-hot from phase 1), apply mix, store.
#pragma unroll
    for (int k = 0; k < 8; ++k) {
        f32x4 x0 = x4[0 * 512 + k * 64 + lane];
        f32x4 x1 = x4[1 * 512 + k * 64 + lane];
        f32x4 x2 = x4[2 * 512 + k * 64 + lane];
        f32x4 x3 = x4[3 * 512 + k * 64 + lane];
#pragma unroll
        for (int r = 0; r < 4; ++r) {
            f32x4 o = M[r * 4 + 0] * x0 + M[r * 4 + 1] * x1
                    + M[r * 4 + 2] * x2 + M[r * 4 + 3] * x3;
            o4[r * 512 + k * 64 + lane] = o;
        }
    }
}

extern "C" void kernel_launch(void* const* d_in, const int* in_sizes, int n_in,
                              void* d_out, int out_size, void* d_ws, size_t ws_size,
                              hipStream_t stream) {
    const float* x  = (const float*)d_in[0];
    const float* Wr = (const float*)d_in[1];
    const float* br = (const float*)d_in[2];
    float* out = (float*)d_out;

    const int tokens = in_sizes[0] / (4 * 2048);   // B*T = 8192
    mchc_fused<<<dim3(tokens / 4), dim3(256), 0, stream>>>(x, Wr, br, out);
}